// Round 13
// baseline (2624.552 us; speedup 1.0000x reference)
//
#include <hip/hip_runtime.h>
#include <stdint.h>

#define NN 50000
#define NE 200000
#define NFEAT 512
#define NHID 256
#define NPART 16     /* partitions of the sorted-edge Kruskal scan */
#define CCPIECE 12288 /* Phase-A LDS edge-piece size */
#define CCMAXR 128   /* max hook rounds per CC piece (converges in ~5-15) */
#define NBLKE 196    /* ceil(NE/1024) radix blocks (edges) */
#define NBLKN 49     /* ceil(NN/1024) radix blocks (nodes) */

typedef unsigned long long u64;
typedef unsigned int u32;
typedef unsigned short u16;

// wall-balanced boundaries for cost(q) = a*PB[q] (redundant prefix-CC pass,
// a~1.8ns/edge) + b*chunk (in-order scan, b~10-12ns/edge): decreasing chunks.
__device__ const int PB[NPART + 1] = {
    0, 33344, 61696, 85760, 106240, 127104, 144256, 158272, 169792,
    179200, 186944, 193280, 198464, 198976, 199424, 199744, 200000};

// order-preserving float -> u32 (strictly monotone), exact round-trip
__device__ __forceinline__ u32 encf(float x) {
  u32 u = __float_as_uint(x);
  return (u & 0x80000000u) ? ~u : (u | 0x80000000u);
}
__device__ __forceinline__ float decf(u32 y) {
  u32 u = (y & 0x80000000u) ? (y ^ 0x80000000u) : ~y;
  return __uint_as_float(u);
}

#define SWZ(c) ((c) ^ ((((c) >> 5) & 7) << 2))

// ---------------- filt = relu(X@W1 + b1) @ W2 + b2  -> (NN x 4) f32 ----------------
__global__ __launch_bounds__(256) void mlp_kernel(
    const float* __restrict__ X, const float* __restrict__ W1,
    const float* __restrict__ b1, const float* __restrict__ W2,
    const float* __restrict__ b2, float* __restrict__ filt)
{
  __shared__ float As[64][33];
  __shared__ float Ws[32][256];
  __shared__ float W2s[256][4];

  const int tid = threadIdx.x;
  const int row0 = blockIdx.x * 64;
  const int tr = tid >> 4, tc = tid & 15;

  for (int i = tid; i < NHID * 4; i += 256) W2s[i >> 2][i & 3] = W2[i];

  float4 acc[4][4];
  #pragma unroll
  for (int i = 0; i < 4; i++)
    #pragma unroll
    for (int q = 0; q < 4; q++) acc[i][q] = make_float4(0.f, 0.f, 0.f, 0.f);

  for (int k0 = 0; k0 < NFEAT; k0 += 32) {
    __syncthreads();
    {
      const int r = tid >> 3, c4 = (tid & 7) << 2;
      #pragma unroll
      for (int rr = 0; rr < 2; rr++) {
        const int row = r + rr * 32;
        const int grow = row0 + row;
        float4 v = make_float4(0.f, 0.f, 0.f, 0.f);
        if (grow < NN) v = *(const float4*)&X[(size_t)grow * NFEAT + k0 + c4];
        As[row][c4 + 0] = v.x; As[row][c4 + 1] = v.y;
        As[row][c4 + 2] = v.z; As[row][c4 + 3] = v.w;
      }
      const int wr = tid >> 6, wc4 = (tid & 63) << 2;
      const int pc = SWZ(wc4);
      #pragma unroll
      for (int rr = 0; rr < 8; rr++) {
        const int rowk = wr + rr * 4;
        float4 v = *(const float4*)&W1[(size_t)(k0 + rowk) * NHID + wc4];
        *(float4*)&Ws[rowk][pc] = v;
      }
    }
    __syncthreads();
    #pragma unroll 8
    for (int kk = 0; kk < 32; kk++) {
      const float a0 = As[tr * 4 + 0][kk], a1 = As[tr * 4 + 1][kk],
                  a2 = As[tr * 4 + 2][kk], a3 = As[tr * 4 + 3][kk];
      #pragma unroll
      for (int q = 0; q < 4; q++) {
        const int col = tc * 16 + q * 4;
        const float4 wv = *(const float4*)&Ws[kk][SWZ(col)];
        acc[0][q].x += a0 * wv.x; acc[0][q].y += a0 * wv.y;
        acc[0][q].z += a0 * wv.z; acc[0][q].w += a0 * wv.w;
        acc[1][q].x += a1 * wv.x; acc[1][q].y += a1 * wv.y;
        acc[1][q].z += a1 * wv.z; acc[1][q].w += a1 * wv.w;
        acc[2][q].x += a2 * wv.x; acc[2][q].y += a2 * wv.y;
        acc[2][q].z += a2 * wv.z; acc[2][q].w += a2 * wv.w;
        acc[3][q].x += a3 * wv.x; acc[3][q].y += a3 * wv.y;
        acc[3][q].w += a3 * wv.w; acc[3][q].z += a3 * wv.z;
      }
    }
  }

  float p[4][4];
  #pragma unroll
  for (int i = 0; i < 4; i++)
    #pragma unroll
    for (int f = 0; f < 4; f++) p[i][f] = 0.f;

  #pragma unroll
  for (int q = 0; q < 4; q++) {
    const int colb = tc * 16 + q * 4;
    float bb[4];
    #pragma unroll
    for (int j = 0; j < 4; j++) bb[j] = b1[colb + j];
    #pragma unroll
    for (int i = 0; i < 4; i++) {
      float h[4] = {acc[i][q].x + bb[0], acc[i][q].y + bb[1],
                    acc[i][q].z + bb[2], acc[i][q].w + bb[3]};
      #pragma unroll
      for (int j = 0; j < 4; j++) {
        const float hh = fmaxf(h[j], 0.f);
        #pragma unroll
        for (int f = 0; f < 4; f++) p[i][f] += hh * W2s[colb + j][f];
      }
    }
  }

  #pragma unroll
  for (int m = 1; m < 16; m <<= 1)
    #pragma unroll
    for (int i = 0; i < 4; i++)
      #pragma unroll
      for (int f = 0; f < 4; f++)
        p[i][f] += __shfl_xor(p[i][f], m, 64);

  if (tc == 0) {
    const float c0 = b2[0], c1 = b2[1], c2 = b2[2], c3 = b2[3];
    #pragma unroll
    for (int i = 0; i < 4; i++) {
      const int row = row0 + tr * 4 + i;
      if (row < NN) {
        float4 o = make_float4(p[i][0] + c0, p[i][1] + c1, p[i][2] + c2, p[i][3] + c3);
        *(float4*)&filt[(size_t)row * 4] = o;
      }
    }
  }
}

__global__ void zero4_kernel(u32* __restrict__ maxv) {
  if (threadIdx.x < 4) maxv[threadIdx.x] = 0u;
}

__global__ __launch_bounds__(256) void maxv_kernel(const float* __restrict__ filt,
                                                   u32* __restrict__ maxv)
{
  __shared__ u32 lm[4];
  if (threadIdx.x < 4) lm[threadIdx.x] = 0u;
  __syncthreads();
  const int n = blockIdx.x * 256 + threadIdx.x;
  if (n < NN) {
    const float4 v = *(const float4*)&filt[(size_t)n * 4];
    atomicMax(&lm[0], encf(v.x));
    atomicMax(&lm[1], encf(v.y));
    atomicMax(&lm[2], encf(v.z));
    atomicMax(&lm[3], encf(v.w));
  }
  __syncthreads();
  if (threadIdx.x < 4) atomicMax(&maxv[threadIdx.x], lm[threadIdx.x]);
}

// ---------------- node sort keys: (enc(v) << 32) | node ----------------
__global__ __launch_bounds__(256) void nodeprep_kernel(const float* __restrict__ filt,
                                                       u64* __restrict__ nodekeys)
{
  const int n = blockIdx.x * 256 + threadIdx.x;
  const int f = blockIdx.y;
  if (n < NN) {
    const float v = filt[(size_t)n * 4 + f];
    nodekeys[(size_t)f * NN + n] = ((u64)encf(v) << 32) | (u32)n;
  }
}

// ---------------- stable LSD radix sort, 8-bit digits of the HIGH word ----------
__global__ __launch_bounds__(256) void radix_hist(
    const u64* __restrict__ src, u32* __restrict__ hist, int n, int nblk, int shift)
{
  __shared__ u32 cnt[256];
  const int tid = threadIdx.x;
  const int blk = blockIdx.x;
  const int f = blockIdx.y;
  src += (size_t)f * n;
  hist += (size_t)f * 256 * nblk;
  cnt[tid] = 0;
  __syncthreads();
  #pragma unroll
  for (int k = 0; k < 4; k++) {
    const int i = blk * 1024 + k * 256 + tid;
    if (i < n) atomicAdd(&cnt[(u32)(src[i] >> shift) & 255u], 1u);
  }
  __syncthreads();
  hist[(size_t)tid * nblk + blk] = cnt[tid];
}

// per-(digit,f) row: exclusive scan over nblk blocks; emit row total
__global__ __launch_bounds__(256) void radix_scan_rows(
    u32* __restrict__ hist, u32* __restrict__ rowtot, int nblk)
{
  __shared__ u32 buf[256];
  const int d = blockIdx.x, f = blockIdx.y;
  const int tid = threadIdx.x;
  u32* row = hist + ((size_t)f * 256 + d) * nblk;
  u32 v = (tid < nblk) ? row[tid] : 0u;
  buf[tid] = v;
  __syncthreads();
  for (int off = 1; off < 256; off <<= 1) {
    const u32 t = (tid >= off) ? buf[tid - off] : 0u;
    __syncthreads();
    buf[tid] += t;
    __syncthreads();
  }
  if (tid < nblk) row[tid] = buf[tid] - v;          // exclusive within row
  if (tid == 255) rowtot[f * 256 + d] = buf[255];   // row total
}

// per-filtration: exclusive scan of the 256 row totals (digit prefix)
__global__ __launch_bounds__(256) void radix_scan_digits(u32* __restrict__ rowtot)
{
  __shared__ u32 buf[256];
  const int f = blockIdx.x, tid = threadIdx.x;
  const u32 v = rowtot[f * 256 + tid];
  buf[tid] = v;
  __syncthreads();
  for (int off = 1; off < 256; off <<= 1) {
    const u32 t = (tid >= off) ? buf[tid - off] : 0u;
    __syncthreads();
    buf[tid] += t;
    __syncthreads();
  }
  rowtot[f * 256 + tid] = buf[tid] - v;             // exclusive digit prefix
}

// stable scatter: global order preserved via (block, round k, wave, lane)
__global__ __launch_bounds__(256) void radix_scatter(
    const u64* __restrict__ src, u64* __restrict__ dst,
    const u32* __restrict__ hist, const u32* __restrict__ rowtot,
    int n, int nblk, int shift)
{
  __shared__ u32 baseD[256];
  __shared__ u32 accum[256];
  __shared__ u32 roundCnt[4 * 256];
  const int tid = threadIdx.x;
  const int blk = blockIdx.x;
  const int f = blockIdx.y;
  const int lane = tid & 63, wid = tid >> 6;
  src += (size_t)f * n;
  dst += (size_t)f * n;
  baseD[tid] = hist[(size_t)f * 256 * nblk + (size_t)tid * nblk + blk] +
               rowtot[f * 256 + tid];
  accum[tid] = 0;
  for (int k = 0; k < 4; k++) {
    roundCnt[tid] = 0; roundCnt[tid + 256] = 0;
    roundCnt[tid + 512] = 0; roundCnt[tid + 768] = 0;
    __syncthreads();
    const int i = blk * 1024 + k * 256 + tid;
    const bool valid = (i < n);
    const u64 key = valid ? src[i] : 0ull;
    const u32 d = (u32)(key >> shift) & 255u;
    u64 peers = __ballot(valid);
    #pragma unroll
    for (int b = 0; b < 8; b++) {
      const u64 bal = __ballot((d >> b) & 1u);
      peers &= ((d >> b) & 1u) ? bal : ~bal;
    }
    const u32 rank = (u32)__popcll(peers & ((1ull << lane) - 1ull));
    if (valid && (__ffsll((long long)peers) - 1 == lane))
      roundCnt[wid * 256 + d] = (u32)__popcll(peers);
    __syncthreads();
    if (valid) {
      u32 off = baseD[d] + accum[d] + rank;
      for (int w2 = 0; w2 < wid; w2++) off += roundCnt[w2 * 256 + d];
      dst[off] = key;
    }
    __syncthreads();
    accum[tid] += roundCnt[tid] + roundCnt[256 + tid] +
                  roundCnt[512 + tid] + roundCnt[768 + tid];
    __syncthreads();
  }
}

// ---------------- rank scatter ----------------
__global__ __launch_bounds__(256) void rank_kernel(const u64* __restrict__ nodekeys,
                                                   u32* __restrict__ rankOf,
                                                   u32* __restrict__ nodeOf)
{
  const int j = blockIdx.x * 256 + threadIdx.x;
  const int f = blockIdx.y;
  if (j < NN) {
    const u64 kk = nodekeys[(size_t)f * NN + j];
    const u32 node = (u32)(kk & 0xffffffffu);
    rankOf[(size_t)f * NN + node] = (u32)j;
    nodeOf[(size_t)f * NN + j] = node;
  }
}

// ---------------- births + essential deaths ----------------
__global__ __launch_bounds__(256) void init_kernel(
    const float* __restrict__ filt, const u32* __restrict__ maxv,
    float* __restrict__ out)
{
  const int n = blockIdx.x * 256 + threadIdx.x;
  const int f = blockIdx.y;
  if (n < NN) {
    const size_t idx = (size_t)f * NN + n;
    out[idx * 2 + 0] = filt[(size_t)n * 4 + f];
    out[idx * 2 + 1] = decf(maxv[f]);
  }
}

// ---------------- per-edge pairs: (w << 32) | (ru<<16 | rt) ----------------
__global__ __launch_bounds__(256) void prep_kernel(
    const int* __restrict__ ei, const float* __restrict__ filt,
    const u32* __restrict__ rankOf, u64* __restrict__ pairs)
{
  const int e = blockIdx.x * 256 + threadIdx.x;
  if (e >= NE) return;
  const int s = ei[e];
  const int d = ei[NE + e];
  const float4 vs = *(const float4*)&filt[(size_t)s * 4];
  const float4 vd = *(const float4*)&filt[(size_t)d * 4];
  float wf[4] = {fmaxf(vs.x, vd.x), fmaxf(vs.y, vd.y),
                 fmaxf(vs.z, vd.z), fmaxf(vs.w, vd.w)};
  #pragma unroll
  for (int f = 0; f < 4; f++) {
    const u32 ru = rankOf[(size_t)f * NN + s];
    const u32 rt = rankOf[(size_t)f * NN + d];
    pairs[(size_t)f * NE + e] = ((u64)encf(wf[f]) << 32) | ((ru << 16) | rt);
  }
}

// ---------------- partitioned Kruskal: hook-only prefix-CC + filtered scan ----
__global__ __launch_bounds__(1024) void uf_kernel(
    const u64* __restrict__ pairs, u64* __restrict__ qbuf, u32* __restrict__ qcnt)
{
  __shared__ __align__(16) u16 par[NN];          // 100,000 B
  __shared__ __align__(16) u32 scratch[CCPIECE]; // 49,152 B: CC pieces / batch hash
  __shared__ u32 chg;
  const int q = blockIdx.x, f = blockIdx.y;
  const int tid = threadIdx.x;
  const u64* ps = pairs + (size_t)f * NE;
  const int lo = PB[q], hi = PB[q + 1];

  // parent = identity
  u32* par32 = (u32*)par;
  for (int j = tid; j < NN / 2; j += 1024)
    par32[j] = ((u32)(2 * j + 1) << 16) | (u32)(2 * j);
  __syncthreads();

  // ---- Phase A: hook-only incremental CC over [0, lo), LDS piece-wise ----
  // No full-array sweeps: each edge does dual path-halving finds + hook-min.
  // chg = "some edge saw unequal roots"; a round with chg==0 is a fixpoint
  // (lost racy updates are retried next round). Min-rank node of a component
  // is never hooked -> root == component min (elder rule's requirement).
  for (int plo = 0; plo < lo; plo += CCPIECE) {
    int phi = plo + CCPIECE; if (phi > lo) phi = lo;
    const int len = phi - plo;
    for (int i = tid; i < len; i += 1024)
      scratch[i] = (u32)(ps[plo + i] & 0xffffffffu);
    __syncthreads();
    for (int r = 0; r < CCMAXR; r++) {
      if (tid == 0) chg = 0u;
      __syncthreads();
      for (int i = tid; i < len; i += 1024) {
        const u32 pr = scratch[i];
        int a = (int)(pr >> 16), b = (int)(pr & 0xffffu);
        u32 pa = par[a], pb = par[b];
        while (pa != (u32)a || pb != (u32)b) {
          const u32 ga = par[pa];
          const u32 gb = par[pb];
          if (pa != (u32)a) { par[a] = (u16)ga; a = (int)ga; }
          if (pb != (u32)b) { par[b] = (u16)gb; b = (int)gb; }
          pa = par[a]; pb = par[b];
        }
        if (a != b) {
          const u32 h = (a > b) ? (u32)a : (u32)b;
          const u32 l = (u32)(a ^ b) ^ h;
          if (l < (u32)par[h]) par[h] = (u16)l;
          chg = 1u;
        }
      }
      __syncthreads();
      if (chg == 0u) break;
      __syncthreads();
    }
    __syncthreads();   // scratch reused next piece
  }
  __syncthreads();

  // ---- Phase B: wave 0 scans [lo, hi) in order ----
  if (tid >= 64) return;
  const int lane = tid;
  u64* qb = qbuf + (size_t)f * NE + lo;
  u32 qcount = 0;
  uint4* h4 = (uint4*)scratch;          // 1024-slot u32 hash = scratch[0..1023]
  const uint4 zz = make_uint4(0u, 0u, 0u, 0u);

  u64 pair0 = ps[lo + lane];            // boundaries are multiples of 64
  u64 pair1 = (lo + 64 < hi) ? ps[lo + 64 + lane] : 0ull;

  for (int base = lo; base < hi; base += 64) {
    u64 pair2 = 0ull;
    if (base + 128 < hi) pair2 = ps[base + 128 + lane];   // 2-deep prefetch

    const u32 pr = (u32)(pair0 & 0xffffffffu);
    const u32 deathw = (u32)(pair0 >> 32);
    const int u = (int)(pr >> 16), t = (int)(pr & 0xffffu);

    // dual interleaved path-halving find in LDS (snapshot before batch merges)
    int ru = u, rt = t;
    u32 pu = par[ru], pt = par[rt];
    while (pu != (u32)ru || pt != (u32)rt) {
      const u32 gu = par[pu];
      const u32 gt = par[pt];
      if (pu != (u32)ru) { par[ru] = (u16)gu; ru = (int)gu; }
      if (pt != (u32)rt) { par[rt] = (u16)gt; rt = (int)gt; }
      pu = par[ru]; pt = par[rt];
    }

    const bool mg = (ru != rt);
    const u32 winv = (ru < rt) ? (u32)ru : (u32)rt;
    const u32 losev = (u32)(ru ^ rt) ^ winv;
    const u64 mball = __ballot(mg);
    const int nm = (int)__popcll(mball);

    // conflict detection (only when >=2 merges could interact): both endpoint
    // roots counted; a lane joins the sequential chain iff its LOSER's hash
    // slot is touched twice (collisions only over-flag -> safe).
    bool flag = false;
    if (nm > 1) {
      #pragma unroll
      for (int k = 0; k < 4; k++) h4[lane + 64 * k] = zz;
      const u32 hu = ((u32)ru * 2654435761u) >> 22;
      const u32 ht = ((u32)rt * 2654435761u) >> 22;
      if (mg) { atomicAdd(&scratch[hu], 1u); atomicAdd(&scratch[ht], 1u); }
      asm volatile("s_waitcnt lgkmcnt(0)" ::: "memory");
      u32 cl = 0u;
      if (mg) cl = scratch[(losev == (u32)ru) ? hu : ht];
      flag = mg && (cl >= 2u);
    }

    u32 myLose = 0xffffffffu, myWin = 0u;
    if (mg && !flag) { myLose = losev; myWin = winv; }   // independent: parallel

    // sequential chain only over flagged lanes (readlane; wave-uniform l)
    u64 chain = __ballot(flag);
    u32 mp = ((u32)ru << 16) | (u32)rt;
    while (chain) {
      const int l = __ffsll((long long)chain) - 1;
      chain &= (chain - 1);
      const u32 ab = (u32)__builtin_amdgcn_readlane((int)mp, l);
      const u32 a = ab >> 16, b = ab & 0xffffu;
      if (a != b) {
        const u32 win = a < b ? a : b;
        const u32 lose = a ^ b ^ win;
        const bool isme = (lane == l);
        myLose = isme ? lose : myLose;
        myWin = isme ? win : myWin;
        const u32 h2 = mp >> 16, l2m = mp & 0xffffu;
        mp = ((h2 == lose ? win : h2) << 16) | (l2m == lose ? win : l2m);
      }
    }

    // epilogue: unique losers -> race-free parallel commit + queued death
    const u64 mmask = __ballot(myLose != 0xffffffffu);
    if (myLose != 0xffffffffu) {
      par[myLose] = (u16)myWin;
      const u32 idx = (u32)__popcll(mmask & ((1ull << lane) - 1ull));
      qb[qcount + idx] = ((u64)deathw << 32) | myLose;
    }
    qcount += (u32)__popcll(mmask);

    asm volatile("s_waitcnt lgkmcnt(0)" ::: "memory");
    __builtin_amdgcn_sched_barrier(0);
    pair0 = pair1; pair1 = pair2;
  }
  if (lane == 0) qcnt[f * NPART + q] = qcount;
}

// ---------------- apply queued deaths: out[ndOf[lose]*2+1] = decf(w) ----------
__global__ __launch_bounds__(256) void finalize_kernel(
    const u64* __restrict__ qbuf, const u32* __restrict__ qcnt,
    const u32* __restrict__ nodeOf, float* __restrict__ out)
{
  const int e = blockIdx.x * 256 + threadIdx.x;
  const int f = blockIdx.y;
  if (e >= NE) return;
  int q = 0;
  while (q < NPART - 1 && e >= PB[q + 1]) q++;
  if ((u32)(e - PB[q]) < qcnt[f * NPART + q]) {
    const u64 v = qbuf[(size_t)f * NE + e];
    const u32 lose = (u32)(v & 0xffffffffu);
    const u32 node = nodeOf[(size_t)f * NN + lose];
    out[((size_t)f * NN + node) * 2 + 1] = decf((u32)(v >> 32));
  }
}

extern "C" void kernel_launch(void* const* d_in, const int* in_sizes, int n_in,
                              void* d_out, int out_size, void* d_ws, size_t ws_size,
                              hipStream_t stream)
{
  const float* X  = (const float*)d_in[0];
  const float* W1 = (const float*)d_in[1];
  const float* b1 = (const float*)d_in[2];
  const float* W2 = (const float*)d_in[3];
  const float* b2 = (const float*)d_in[4];
  const int*   EI = (const int*)d_in[5];   // int32 per harness contract
  float* out = (float*)d_out;

  char* w = (char*)d_ws;
  u64*  A      = (u64*)w;   w += (size_t)4 * NE * sizeof(u64);   // 6,400,000
  char* Bb     = w;         w += (size_t)4 * NE * sizeof(u64);   // 6,400,000
  u64*  qbuf   = (u64*)w;   w += (size_t)4 * NE * sizeof(u64);   // 6,400,000
  float* filt  = (float*)w; w += (size_t)NN * 4 * sizeof(float); //   800,000
  u32*  rankOf = (u32*)w;   w += (size_t)4 * NN * sizeof(u32);   //   800,000
  u32*  nodeOf = (u32*)w;   w += (size_t)4 * NN * sizeof(u32);   //   800,000
  u32*  qcnt   = (u32*)w;   w += 64 * sizeof(u32);
  u32*  rowtot = (u32*)w;   w += 4 * 256 * sizeof(u32);
  u32*  maxv   = (u32*)w;   w += 4 * sizeof(u32);

  // aliases into B (time-disjoint): node sort ping/pong early, edge pong later.
  u64* NA   = (u64*)Bb;
  u64* NB   = (u64*)(Bb + 1600000);
  u64* EB   = (u64*)Bb;
  u32* nhist = rankOf;          // 200,704 B <= 800,000 (before rank_kernel)
  u32* ehist = (u32*)filt;      // 802,816 B (filt+rankOf dead after prep)

  const size_t need = (size_t)(w - (char*)d_ws);
  if (ws_size < need) return;

  const int nodeBlocks = (NN + 255) / 256;
  const int edgeBlocks = (NE + 255) / 256;

  zero4_kernel<<<dim3(1), dim3(64), 0, stream>>>(maxv);
  mlp_kernel<<<dim3((NN + 63) / 64), dim3(256), 0, stream>>>(X, W1, b1, W2, b2, filt);
  maxv_kernel<<<dim3(nodeBlocks, 1), dim3(256), 0, stream>>>(filt, maxv);
  nodeprep_kernel<<<dim3(nodeBlocks, 4), dim3(256), 0, stream>>>(filt, NA);

  // node sort: 4 stable LSD passes on enc(v) (bits 32..63); final lands in NA
  {
    u64 *s = NA, *d = NB;
    for (int p = 0; p < 4; p++) {
      const int sh = 32 + 8 * p;
      radix_hist<<<dim3(NBLKN, 4), dim3(256), 0, stream>>>(s, nhist, NN, NBLKN, sh);
      radix_scan_rows<<<dim3(256, 4), dim3(256), 0, stream>>>(nhist, rowtot, NBLKN);
      radix_scan_digits<<<dim3(4), dim3(256), 0, stream>>>(rowtot);
      radix_scatter<<<dim3(NBLKN, 4), dim3(256), 0, stream>>>(s, d, nhist, rowtot,
                                                              NN, NBLKN, sh);
      u64* t = s; s = d; d = t;
    }
  }

  rank_kernel<<<dim3(nodeBlocks, 4), dim3(256), 0, stream>>>(NA, rankOf, nodeOf);
  init_kernel<<<dim3(nodeBlocks, 4), dim3(256), 0, stream>>>(filt, maxv, out);
  prep_kernel<<<dim3(edgeBlocks, 1), dim3(256), 0, stream>>>(EI, filt, rankOf, A);

  // edge sort: 4 stable LSD passes on w (bits 32..63); final lands in A
  {
    u64 *s = A, *d = EB;
    for (int p = 0; p < 4; p++) {
      const int sh = 32 + 8 * p;
      radix_hist<<<dim3(NBLKE, 4), dim3(256), 0, stream>>>(s, ehist, NE, NBLKE, sh);
      radix_scan_rows<<<dim3(256, 4), dim3(256), 0, stream>>>(ehist, rowtot, NBLKE);
      radix_scan_digits<<<dim3(4), dim3(256), 0, stream>>>(rowtot);
      radix_scatter<<<dim3(NBLKE, 4), dim3(256), 0, stream>>>(s, d, ehist, rowtot,
                                                              NE, NBLKE, sh);
      u64* t = s; s = d; d = t;
    }
  }

  // partitioned scans (hook-only prefix-CC per block, then wave-0 ordered scan)
  uf_kernel<<<dim3(NPART, 4), dim3(1024), 0, stream>>>(A, qbuf, qcnt);

  // apply queued deaths
  finalize_kernel<<<dim3(edgeBlocks, 4), dim3(256), 0, stream>>>(qbuf, qcnt, nodeOf, out);
}

// Round 14
// 1172.305 us; speedup vs baseline: 2.2388x; 2.2388x over previous
//
#include <hip/hip_runtime.h>
#include <stdint.h>

#define NN 50000
#define NE 200000
#define NFEAT 512
#define NHID 256
#define NPART 32     /* partitions of the sorted-edge Kruskal scan */
#define NBLKE 196    /* ceil(NE/1024) radix blocks (edges) */
#define NBLKN 49     /* ceil(NN/1024) radix blocks (nodes) */

typedef unsigned long long u64;
typedef unsigned int u32;
typedef unsigned short u16;

// wall-balanced boundaries for cost(q) = a*PB[q] (lock-free prefix-UF pass,
// a~0.5ns/edge) + b*chunk (in-order scan, b~10.2ns/edge): T~125us,
// Dq = (T - a*PB[q])/b, all multiples of 64.
__device__ const int PB[NPART + 1] = {
    0, 12288, 23936, 35008, 45568, 55616, 65152, 74240, 82880,
    91072, 98880, 106304, 113344, 120064, 126464, 132544, 138304,
    143808, 148992, 153920, 158656, 163136, 167424, 171456, 175296,
    178944, 182464, 185792, 188928, 191936, 194816, 197504, 200000};

// order-preserving float -> u32 (strictly monotone), exact round-trip
__device__ __forceinline__ u32 encf(float x) {
  u32 u = __float_as_uint(x);
  return (u & 0x80000000u) ? ~u : (u | 0x80000000u);
}
__device__ __forceinline__ float decf(u32 y) {
  u32 u = (y & 0x80000000u) ? (y ^ 0x80000000u) : ~y;
  return __uint_as_float(u);
}

#define SWZ(c) ((c) ^ ((((c) >> 5) & 7) << 2))

// ---------------- filt = relu(X@W1 + b1) @ W2 + b2  -> (NN x 4) f32 ----------------
__global__ __launch_bounds__(256) void mlp_kernel(
    const float* __restrict__ X, const float* __restrict__ W1,
    const float* __restrict__ b1, const float* __restrict__ W2,
    const float* __restrict__ b2, float* __restrict__ filt)
{
  __shared__ float As[64][33];
  __shared__ float Ws[32][256];
  __shared__ float W2s[256][4];

  const int tid = threadIdx.x;
  const int row0 = blockIdx.x * 64;
  const int tr = tid >> 4, tc = tid & 15;

  for (int i = tid; i < NHID * 4; i += 256) W2s[i >> 2][i & 3] = W2[i];

  float4 acc[4][4];
  #pragma unroll
  for (int i = 0; i < 4; i++)
    #pragma unroll
    for (int q = 0; q < 4; q++) acc[i][q] = make_float4(0.f, 0.f, 0.f, 0.f);

  for (int k0 = 0; k0 < NFEAT; k0 += 32) {
    __syncthreads();
    {
      const int r = tid >> 3, c4 = (tid & 7) << 2;
      #pragma unroll
      for (int rr = 0; rr < 2; rr++) {
        const int row = r + rr * 32;
        const int grow = row0 + row;
        float4 v = make_float4(0.f, 0.f, 0.f, 0.f);
        if (grow < NN) v = *(const float4*)&X[(size_t)grow * NFEAT + k0 + c4];
        As[row][c4 + 0] = v.x; As[row][c4 + 1] = v.y;
        As[row][c4 + 2] = v.z; As[row][c4 + 3] = v.w;
      }
      const int wr = tid >> 6, wc4 = (tid & 63) << 2;
      const int pc = SWZ(wc4);
      #pragma unroll
      for (int rr = 0; rr < 8; rr++) {
        const int rowk = wr + rr * 4;
        float4 v = *(const float4*)&W1[(size_t)(k0 + rowk) * NHID + wc4];
        *(float4*)&Ws[rowk][pc] = v;
      }
    }
    __syncthreads();
    #pragma unroll 8
    for (int kk = 0; kk < 32; kk++) {
      const float a0 = As[tr * 4 + 0][kk], a1 = As[tr * 4 + 1][kk],
                  a2 = As[tr * 4 + 2][kk], a3 = As[tr * 4 + 3][kk];
      #pragma unroll
      for (int q = 0; q < 4; q++) {
        const int col = tc * 16 + q * 4;
        const float4 wv = *(const float4*)&Ws[kk][SWZ(col)];
        acc[0][q].x += a0 * wv.x; acc[0][q].y += a0 * wv.y;
        acc[0][q].z += a0 * wv.z; acc[0][q].w += a0 * wv.w;
        acc[1][q].x += a1 * wv.x; acc[1][q].y += a1 * wv.y;
        acc[1][q].z += a1 * wv.z; acc[1][q].w += a1 * wv.w;
        acc[2][q].x += a2 * wv.x; acc[2][q].y += a2 * wv.y;
        acc[2][q].z += a2 * wv.z; acc[2][q].w += a2 * wv.w;
        acc[3][q].x += a3 * wv.x; acc[3][q].y += a3 * wv.y;
        acc[3][q].w += a3 * wv.w; acc[3][q].z += a3 * wv.z;
      }
    }
  }

  float p[4][4];
  #pragma unroll
  for (int i = 0; i < 4; i++)
    #pragma unroll
    for (int f = 0; f < 4; f++) p[i][f] = 0.f;

  #pragma unroll
  for (int q = 0; q < 4; q++) {
    const int colb = tc * 16 + q * 4;
    float bb[4];
    #pragma unroll
    for (int j = 0; j < 4; j++) bb[j] = b1[colb + j];
    #pragma unroll
    for (int i = 0; i < 4; i++) {
      float h[4] = {acc[i][q].x + bb[0], acc[i][q].y + bb[1],
                    acc[i][q].z + bb[2], acc[i][q].w + bb[3]};
      #pragma unroll
      for (int j = 0; j < 4; j++) {
        const float hh = fmaxf(h[j], 0.f);
        #pragma unroll
        for (int f = 0; f < 4; f++) p[i][f] += hh * W2s[colb + j][f];
      }
    }
  }

  #pragma unroll
  for (int m = 1; m < 16; m <<= 1)
    #pragma unroll
    for (int i = 0; i < 4; i++)
      #pragma unroll
      for (int f = 0; f < 4; f++)
        p[i][f] += __shfl_xor(p[i][f], m, 64);

  if (tc == 0) {
    const float c0 = b2[0], c1 = b2[1], c2 = b2[2], c3 = b2[3];
    #pragma unroll
    for (int i = 0; i < 4; i++) {
      const int row = row0 + tr * 4 + i;
      if (row < NN) {
        float4 o = make_float4(p[i][0] + c0, p[i][1] + c1, p[i][2] + c2, p[i][3] + c3);
        *(float4*)&filt[(size_t)row * 4] = o;
      }
    }
  }
}

__global__ void zero4_kernel(u32* __restrict__ maxv) {
  if (threadIdx.x < 4) maxv[threadIdx.x] = 0u;
}

__global__ __launch_bounds__(256) void maxv_kernel(const float* __restrict__ filt,
                                                   u32* __restrict__ maxv)
{
  __shared__ u32 lm[4];
  if (threadIdx.x < 4) lm[threadIdx.x] = 0u;
  __syncthreads();
  const int n = blockIdx.x * 256 + threadIdx.x;
  if (n < NN) {
    const float4 v = *(const float4*)&filt[(size_t)n * 4];
    atomicMax(&lm[0], encf(v.x));
    atomicMax(&lm[1], encf(v.y));
    atomicMax(&lm[2], encf(v.z));
    atomicMax(&lm[3], encf(v.w));
  }
  __syncthreads();
  if (threadIdx.x < 4) atomicMax(&maxv[threadIdx.x], lm[threadIdx.x]);
}

// ---------------- node sort keys: (enc(v) << 32) | node ----------------
__global__ __launch_bounds__(256) void nodeprep_kernel(const float* __restrict__ filt,
                                                       u64* __restrict__ nodekeys)
{
  const int n = blockIdx.x * 256 + threadIdx.x;
  const int f = blockIdx.y;
  if (n < NN) {
    const float v = filt[(size_t)n * 4 + f];
    nodekeys[(size_t)f * NN + n] = ((u64)encf(v) << 32) | (u32)n;
  }
}

// ---------------- stable LSD radix sort, 8-bit digits of the HIGH word ----------
__global__ __launch_bounds__(256) void radix_hist(
    const u64* __restrict__ src, u32* __restrict__ hist, int n, int nblk, int shift)
{
  __shared__ u32 cnt[256];
  const int tid = threadIdx.x;
  const int blk = blockIdx.x;
  const int f = blockIdx.y;
  src += (size_t)f * n;
  hist += (size_t)f * 256 * nblk;
  cnt[tid] = 0;
  __syncthreads();
  #pragma unroll
  for (int k = 0; k < 4; k++) {
    const int i = blk * 1024 + k * 256 + tid;
    if (i < n) atomicAdd(&cnt[(u32)(src[i] >> shift) & 255u], 1u);
  }
  __syncthreads();
  hist[(size_t)tid * nblk + blk] = cnt[tid];
}

// per-(digit,f) row: exclusive scan over nblk blocks; emit row total
__global__ __launch_bounds__(256) void radix_scan_rows(
    u32* __restrict__ hist, u32* __restrict__ rowtot, int nblk)
{
  __shared__ u32 buf[256];
  const int d = blockIdx.x, f = blockIdx.y;
  const int tid = threadIdx.x;
  u32* row = hist + ((size_t)f * 256 + d) * nblk;
  u32 v = (tid < nblk) ? row[tid] : 0u;
  buf[tid] = v;
  __syncthreads();
  for (int off = 1; off < 256; off <<= 1) {
    const u32 t = (tid >= off) ? buf[tid - off] : 0u;
    __syncthreads();
    buf[tid] += t;
    __syncthreads();
  }
  if (tid < nblk) row[tid] = buf[tid] - v;          // exclusive within row
  if (tid == 255) rowtot[f * 256 + d] = buf[255];   // row total
}

// per-filtration: exclusive scan of the 256 row totals (digit prefix)
__global__ __launch_bounds__(256) void radix_scan_digits(u32* __restrict__ rowtot)
{
  __shared__ u32 buf[256];
  const int f = blockIdx.x, tid = threadIdx.x;
  const u32 v = rowtot[f * 256 + tid];
  buf[tid] = v;
  __syncthreads();
  for (int off = 1; off < 256; off <<= 1) {
    const u32 t = (tid >= off) ? buf[tid - off] : 0u;
    __syncthreads();
    buf[tid] += t;
    __syncthreads();
  }
  rowtot[f * 256 + tid] = buf[tid] - v;             // exclusive digit prefix
}

// stable scatter: global order preserved via (block, round k, wave, lane)
__global__ __launch_bounds__(256) void radix_scatter(
    const u64* __restrict__ src, u64* __restrict__ dst,
    const u32* __restrict__ hist, const u32* __restrict__ rowtot,
    int n, int nblk, int shift)
{
  __shared__ u32 baseD[256];
  __shared__ u32 accum[256];
  __shared__ u32 roundCnt[4 * 256];
  const int tid = threadIdx.x;
  const int blk = blockIdx.x;
  const int f = blockIdx.y;
  const int lane = tid & 63, wid = tid >> 6;
  src += (size_t)f * n;
  dst += (size_t)f * n;
  baseD[tid] = hist[(size_t)f * 256 * nblk + (size_t)tid * nblk + blk] +
               rowtot[f * 256 + tid];
  accum[tid] = 0;
  for (int k = 0; k < 4; k++) {
    roundCnt[tid] = 0; roundCnt[tid + 256] = 0;
    roundCnt[tid + 512] = 0; roundCnt[tid + 768] = 0;
    __syncthreads();
    const int i = blk * 1024 + k * 256 + tid;
    const bool valid = (i < n);
    const u64 key = valid ? src[i] : 0ull;
    const u32 d = (u32)(key >> shift) & 255u;
    u64 peers = __ballot(valid);
    #pragma unroll
    for (int b = 0; b < 8; b++) {
      const u64 bal = __ballot((d >> b) & 1u);
      peers &= ((d >> b) & 1u) ? bal : ~bal;
    }
    const u32 rank = (u32)__popcll(peers & ((1ull << lane) - 1ull));
    if (valid && (__ffsll((long long)peers) - 1 == lane))
      roundCnt[wid * 256 + d] = (u32)__popcll(peers);
    __syncthreads();
    if (valid) {
      u32 off = baseD[d] + accum[d] + rank;
      for (int w2 = 0; w2 < wid; w2++) off += roundCnt[w2 * 256 + d];
      dst[off] = key;
    }
    __syncthreads();
    accum[tid] += roundCnt[tid] + roundCnt[256 + tid] +
                  roundCnt[512 + tid] + roundCnt[768 + tid];
    __syncthreads();
  }
}

// ---------------- rank scatter ----------------
__global__ __launch_bounds__(256) void rank_kernel(const u64* __restrict__ nodekeys,
                                                   u32* __restrict__ rankOf,
                                                   u32* __restrict__ nodeOf)
{
  const int j = blockIdx.x * 256 + threadIdx.x;
  const int f = blockIdx.y;
  if (j < NN) {
    const u64 kk = nodekeys[(size_t)f * NN + j];
    const u32 node = (u32)(kk & 0xffffffffu);
    rankOf[(size_t)f * NN + node] = (u32)j;
    nodeOf[(size_t)f * NN + j] = node;
  }
}

// ---------------- births + essential deaths ----------------
__global__ __launch_bounds__(256) void init_kernel(
    const float* __restrict__ filt, const u32* __restrict__ maxv,
    float* __restrict__ out)
{
  const int n = blockIdx.x * 256 + threadIdx.x;
  const int f = blockIdx.y;
  if (n < NN) {
    const size_t idx = (size_t)f * NN + n;
    out[idx * 2 + 0] = filt[(size_t)n * 4 + f];
    out[idx * 2 + 1] = decf(maxv[f]);
  }
}

// ---------------- per-edge pairs: (w << 32) | (ru<<16 | rt) ----------------
__global__ __launch_bounds__(256) void prep_kernel(
    const int* __restrict__ ei, const float* __restrict__ filt,
    const u32* __restrict__ rankOf, u64* __restrict__ pairs)
{
  const int e = blockIdx.x * 256 + threadIdx.x;
  if (e >= NE) return;
  const int s = ei[e];
  const int d = ei[NE + e];
  const float4 vs = *(const float4*)&filt[(size_t)s * 4];
  const float4 vd = *(const float4*)&filt[(size_t)d * 4];
  float wf[4] = {fmaxf(vs.x, vd.x), fmaxf(vs.y, vd.y),
                 fmaxf(vs.z, vd.z), fmaxf(vs.w, vd.w)};
  #pragma unroll
  for (int f = 0; f < 4; f++) {
    const u32 ru = rankOf[(size_t)f * NN + s];
    const u32 rt = rankOf[(size_t)f * NN + d];
    pairs[(size_t)f * NE + e] = ((u64)encf(wf[f]) << 32) | ((ru << 16) | rt);
  }
}

// ---------------- partitioned Kruskal: lock-free prefix-UF + filtered scan ----
__global__ __launch_bounds__(1024) void uf_kernel(
    const u64* __restrict__ pairs, u64* __restrict__ qbuf, u32* __restrict__ qcnt)
{
  __shared__ __align__(16) u16 par[NN];      // 100,000 B
  __shared__ __align__(16) u32 scratch[1024]; // Phase-B conflict hash
  const int q = blockIdx.x, f = blockIdx.y;
  const int tid = threadIdx.x;
  const u64* ps = pairs + (size_t)f * NE;
  const int lo = PB[q], hi = PB[q + 1];

  // parent = identity
  u32* par32 = (u32*)par;
  for (int j = tid; j < NN / 2; j += 1024)
    par32[j] = ((u32)(2 * j + 1) << 16) | (u32)(2 * j);
  __syncthreads();

  // ---- Phase A: single-pass lock-free UF over [0, lo) (ECL-CC style) ----
  // find: path-halving with plain u16 writes (every written value is a valid
  //   ancestor -> connectivity preserved under races).
  // hook: max-root under min-root via 16-bit CAS in the containing u32 word
  //   (full-word compare -> cross-half races just retry). Roots only ever
  //   decrease -> acyclic, terminates, root == component MIN (elder rule).
  {
    volatile u16* vpar = par;
    for (int e = tid; e < lo; e += 1024) {
      const u32 pr = (u32)(ps[e] & 0xffffffffu);
      u32 x = pr >> 16, y = pr & 0xffffu;
      while (true) {
        u32 px = vpar[x];
        while (px != x) { const u32 g = vpar[px]; vpar[x] = (u16)g; x = g; px = vpar[x]; }
        u32 py = vpar[y];
        while (py != y) { const u32 g = vpar[py]; vpar[y] = (u16)g; y = g; py = vpar[y]; }
        if (x == y) break;
        const u32 h = (x > y) ? x : y;
        const u32 l = x ^ y ^ h;
        volatile u32* w32 = (volatile u32*)par32 + (h >> 1);
        const bool hiH = (h & 1u) != 0u;
        bool hooked = false, lost = false;
        while (!hooked && !lost) {
          const u32 cur = *w32;
          const u32 half = hiH ? (cur >> 16) : (cur & 0xffffu);
          if (half != h) { lost = true; break; }     // h no longer root
          const u32 nw = hiH ? ((cur & 0x0000ffffu) | (l << 16))
                             : ((cur & 0xffff0000u) | l);
          if (atomicCAS((u32*)w32, cur, nw) == cur) hooked = true;
        }
        if (hooked) break;
        x = h; y = l;   // re-find and retry
      }
    }
  }
  __syncthreads();

  // ---- Phase B: wave 0 scans [lo, hi) in order ----
  if (tid >= 64) return;
  const int lane = tid;
  u64* qb = qbuf + (size_t)f * NE + lo;
  u32 qcount = 0;
  uint4* h4 = (uint4*)scratch;          // 1024-slot u32 hash
  const uint4 zz = make_uint4(0u, 0u, 0u, 0u);

  u64 pair0 = ps[lo + lane];            // boundaries are multiples of 64
  u64 pair1 = (lo + 64 < hi) ? ps[lo + 64 + lane] : 0ull;

  for (int base = lo; base < hi; base += 64) {
    u64 pair2 = 0ull;
    if (base + 128 < hi) pair2 = ps[base + 128 + lane];   // 2-deep prefetch

    const u32 pr = (u32)(pair0 & 0xffffffffu);
    const u32 deathw = (u32)(pair0 >> 32);
    const int u = (int)(pr >> 16), t = (int)(pr & 0xffffu);

    // dual interleaved path-halving find in LDS (quiescent between batches)
    int ru = u, rt = t;
    u32 pu = par[ru], pt = par[rt];
    while (pu != (u32)ru || pt != (u32)rt) {
      const u32 gu = par[pu];
      const u32 gt = par[pt];
      if (pu != (u32)ru) { par[ru] = (u16)gu; ru = (int)gu; }
      if (pt != (u32)rt) { par[rt] = (u16)gt; rt = (int)gt; }
      pu = par[ru]; pt = par[rt];
    }

    const bool mg = (ru != rt);
    const u32 winv = (ru < rt) ? (u32)ru : (u32)rt;
    const u32 losev = (u32)(ru ^ rt) ^ winv;
    const u64 mball = __ballot(mg);
    const int nm = (int)__popcll(mball);

    // conflict detection (only when >=2 merges could interact): both endpoint
    // roots counted; a lane joins the sequential chain iff its LOSER's hash
    // slot is touched twice (collisions only over-flag -> safe).
    bool flag = false;
    if (nm > 1) {
      #pragma unroll
      for (int k = 0; k < 4; k++) h4[lane + 64 * k] = zz;
      const u32 hu = ((u32)ru * 2654435761u) >> 22;
      const u32 ht = ((u32)rt * 2654435761u) >> 22;
      if (mg) { atomicAdd(&scratch[hu], 1u); atomicAdd(&scratch[ht], 1u); }
      asm volatile("s_waitcnt lgkmcnt(0)" ::: "memory");
      u32 cl = 0u;
      if (mg) cl = scratch[(losev == (u32)ru) ? hu : ht];
      flag = mg && (cl >= 2u);
    }

    u32 myLose = 0xffffffffu, myWin = 0u;
    if (mg && !flag) { myLose = losev; myWin = winv; }   // independent: parallel

    // sequential chain only over flagged lanes (readlane; wave-uniform l)
    u64 chain = __ballot(flag);
    u32 mp = ((u32)ru << 16) | (u32)rt;
    while (chain) {
      const int l = __ffsll((long long)chain) - 1;
      chain &= (chain - 1);
      const u32 ab = (u32)__builtin_amdgcn_readlane((int)mp, l);
      const u32 a = ab >> 16, b = ab & 0xffffu;
      if (a != b) {
        const u32 win = a < b ? a : b;
        const u32 lose = a ^ b ^ win;
        const bool isme = (lane == l);
        myLose = isme ? lose : myLose;
        myWin = isme ? win : myWin;
        const u32 h2 = mp >> 16, l2m = mp & 0xffffu;
        mp = ((h2 == lose ? win : h2) << 16) | (l2m == lose ? win : l2m);
      }
    }

    // epilogue: unique losers -> race-free parallel commit + queued death
    const u64 mmask = __ballot(myLose != 0xffffffffu);
    if (myLose != 0xffffffffu) {
      par[myLose] = (u16)myWin;
      const u32 idx = (u32)__popcll(mmask & ((1ull << lane) - 1ull));
      qb[qcount + idx] = ((u64)deathw << 32) | myLose;
    }
    qcount += (u32)__popcll(mmask);

    asm volatile("s_waitcnt lgkmcnt(0)" ::: "memory");
    __builtin_amdgcn_sched_barrier(0);
    pair0 = pair1; pair1 = pair2;
  }
  if (lane == 0) qcnt[f * NPART + q] = qcount;
}

// ---------------- apply queued deaths: out[ndOf[lose]*2+1] = decf(w) ----------
__global__ __launch_bounds__(256) void finalize_kernel(
    const u64* __restrict__ qbuf, const u32* __restrict__ qcnt,
    const u32* __restrict__ nodeOf, float* __restrict__ out)
{
  const int e = blockIdx.x * 256 + threadIdx.x;
  const int f = blockIdx.y;
  if (e >= NE) return;
  int q = 0;
  while (q < NPART - 1 && e >= PB[q + 1]) q++;
  if ((u32)(e - PB[q]) < qcnt[f * NPART + q]) {
    const u64 v = qbuf[(size_t)f * NE + e];
    const u32 lose = (u32)(v & 0xffffffffu);
    const u32 node = nodeOf[(size_t)f * NN + lose];
    out[((size_t)f * NN + node) * 2 + 1] = decf((u32)(v >> 32));
  }
}

extern "C" void kernel_launch(void* const* d_in, const int* in_sizes, int n_in,
                              void* d_out, int out_size, void* d_ws, size_t ws_size,
                              hipStream_t stream)
{
  const float* X  = (const float*)d_in[0];
  const float* W1 = (const float*)d_in[1];
  const float* b1 = (const float*)d_in[2];
  const float* W2 = (const float*)d_in[3];
  const float* b2 = (const float*)d_in[4];
  const int*   EI = (const int*)d_in[5];   // int32 per harness contract
  float* out = (float*)d_out;

  char* w = (char*)d_ws;
  u64*  A      = (u64*)w;   w += (size_t)4 * NE * sizeof(u64);   // 6,400,000
  char* Bb     = w;         w += (size_t)4 * NE * sizeof(u64);   // 6,400,000
  u64*  qbuf   = (u64*)w;   w += (size_t)4 * NE * sizeof(u64);   // 6,400,000
  float* filt  = (float*)w; w += (size_t)NN * 4 * sizeof(float); //   800,000
  u32*  rankOf = (u32*)w;   w += (size_t)4 * NN * sizeof(u32);   //   800,000
  u32*  nodeOf = (u32*)w;   w += (size_t)4 * NN * sizeof(u32);   //   800,000
  u32*  qcnt   = (u32*)w;   w += 128 * sizeof(u32);
  u32*  rowtot = (u32*)w;   w += 4 * 256 * sizeof(u32);
  u32*  maxv   = (u32*)w;   w += 4 * sizeof(u32);

  // aliases into B (time-disjoint): node sort ping/pong early, edge pong later.
  u64* NA   = (u64*)Bb;
  u64* NB   = (u64*)(Bb + 1600000);
  u64* EB   = (u64*)Bb;
  u32* nhist = rankOf;          // 200,704 B <= 800,000 (before rank_kernel)
  u32* ehist = (u32*)filt;      // 802,816 B (filt+rankOf dead after prep)

  const size_t need = (size_t)(w - (char*)d_ws);
  if (ws_size < need) return;

  const int nodeBlocks = (NN + 255) / 256;
  const int edgeBlocks = (NE + 255) / 256;

  zero4_kernel<<<dim3(1), dim3(64), 0, stream>>>(maxv);
  mlp_kernel<<<dim3((NN + 63) / 64), dim3(256), 0, stream>>>(X, W1, b1, W2, b2, filt);
  maxv_kernel<<<dim3(nodeBlocks, 1), dim3(256), 0, stream>>>(filt, maxv);
  nodeprep_kernel<<<dim3(nodeBlocks, 4), dim3(256), 0, stream>>>(filt, NA);

  // node sort: 4 stable LSD passes on enc(v) (bits 32..63); final lands in NA
  {
    u64 *s = NA, *d = NB;
    for (int p = 0; p < 4; p++) {
      const int sh = 32 + 8 * p;
      radix_hist<<<dim3(NBLKN, 4), dim3(256), 0, stream>>>(s, nhist, NN, NBLKN, sh);
      radix_scan_rows<<<dim3(256, 4), dim3(256), 0, stream>>>(nhist, rowtot, NBLKN);
      radix_scan_digits<<<dim3(4), dim3(256), 0, stream>>>(rowtot);
      radix_scatter<<<dim3(NBLKN, 4), dim3(256), 0, stream>>>(s, d, nhist, rowtot,
                                                              NN, NBLKN, sh);
      u64* t = s; s = d; d = t;
    }
  }

  rank_kernel<<<dim3(nodeBlocks, 4), dim3(256), 0, stream>>>(NA, rankOf, nodeOf);
  init_kernel<<<dim3(nodeBlocks, 4), dim3(256), 0, stream>>>(filt, maxv, out);
  prep_kernel<<<dim3(edgeBlocks, 1), dim3(256), 0, stream>>>(EI, filt, rankOf, A);

  // edge sort: 4 stable LSD passes on w (bits 32..63); final lands in A
  {
    u64 *s = A, *d = EB;
    for (int p = 0; p < 4; p++) {
      const int sh = 32 + 8 * p;
      radix_hist<<<dim3(NBLKE, 4), dim3(256), 0, stream>>>(s, ehist, NE, NBLKE, sh);
      radix_scan_rows<<<dim3(256, 4), dim3(256), 0, stream>>>(ehist, rowtot, NBLKE);
      radix_scan_digits<<<dim3(4), dim3(256), 0, stream>>>(rowtot);
      radix_scatter<<<dim3(NBLKE, 4), dim3(256), 0, stream>>>(s, d, ehist, rowtot,
                                                              NE, NBLKE, sh);
      u64* t = s; s = d; d = t;
    }
  }

  // partitioned scans (lock-free prefix-UF per block, then wave-0 ordered scan)
  uf_kernel<<<dim3(NPART, 4), dim3(1024), 0, stream>>>(A, qbuf, qcnt);

  // apply queued deaths
  finalize_kernel<<<dim3(edgeBlocks, 4), dim3(256), 0, stream>>>(qbuf, qcnt, nodeOf, out);
}